// Round 3
// baseline (453.226 us; speedup 1.0000x reference)
//
#include <hip/hip_runtime.h>
#include <hip/hip_bf16.h>

#define BB 64
#define SS 4096
#define HH 256
#define AA 128

typedef _Float16 half8v __attribute__((ext_vector_type(8)));
typedef float floatx16 __attribute__((ext_vector_type(16)));

__device__ __forceinline__ float fast_tanh(float x) {
    float xc = fminf(fmaxf(x, -9.0f), 9.0f);
    float e = __expf(2.0f * xc);
    return 1.0f - __fdividef(2.0f, e + 1.0f);
}

// ---------------------------------------------------------------------------
// K0: W1 [H=256][A=128] fp32  ->  Wt [A=128][H=256] f16 (transposed) in d_ws
// ---------------------------------------------------------------------------
__global__ void convert_w1(const float* __restrict__ W1, _Float16* __restrict__ Wt) {
    int n = blockIdx.x;    // 0..127 (A)
    int k = threadIdx.x;   // 0..255 (H)
    Wt[n * HH + k] = (_Float16)W1[k * AA + n];
}

// ---------------------------------------------------------------------------
// K1: scores[m] = tanh(X[m,:]@W1 + b1) @ W2 + b2 — LDS-free, barrier-free
// streaming MFMA GEMM. Block = 4 waves; wave handles 32 rows x all 128 cols
// (4 n-tiles of 32x32x16_f16, fp32 accum). A-frags stream from global with
// in-register fp32->f16 cvt; B-frags reload from 64KB L1/L2-resident Wt.
// A layout: m=lane&31, k=(lane>>5)*8+j.  B layout: n=lane&31, k=(lane>>5)*8+j.
// C layout: col=lane&31, row=(r&3)+8*(r>>2)+4*(lane>>5)  [verified R2].
// ---------------------------------------------------------------------------
__global__ __launch_bounds__(256) void score_stream(
    const float* __restrict__ X,        // [B*S, H]
    const _Float16* __restrict__ Wt,    // [A, H] f16
    const float* __restrict__ b1,       // [A]
    const float* __restrict__ W2,       // [A]
    const float* __restrict__ b2,       // [1]
    float* __restrict__ scores)         // [B*S]
{
    const int tid   = threadIdx.x;
    const int wid   = tid >> 6;
    const int lane  = tid & 63;
    const int lrow  = lane & 31;
    const int lhalf = lane >> 5;
    const int m0    = blockIdx.x * 128 + wid * 32;   // wave's row base

    const float* xp = X + (size_t)(m0 + lrow) * HH + lhalf * 8;

    floatx16 acc[4];
    #pragma unroll
    for (int nt = 0; nt < 4; ++nt)
        #pragma unroll
        for (int r = 0; r < 16; ++r) acc[nt][r] = 0.0f;

    #pragma unroll
    for (int kk = 0; kk < 16; ++kk) {            // K = 16 steps of 16
        float4 v0 = *(const float4*)(xp + kk * 16);
        float4 v1 = *(const float4*)(xp + kk * 16 + 4);
        half8v a;
        a[0] = (_Float16)v0.x; a[1] = (_Float16)v0.y;
        a[2] = (_Float16)v0.z; a[3] = (_Float16)v0.w;
        a[4] = (_Float16)v1.x; a[5] = (_Float16)v1.y;
        a[6] = (_Float16)v1.z; a[7] = (_Float16)v1.w;
        #pragma unroll
        for (int nt = 0; nt < 4; ++nt) {
            half8v b = *(const half8v*)(Wt + (size_t)(nt * 32 + lrow) * HH
                                        + kk * 16 + lhalf * 8);
            acc[nt] = __builtin_amdgcn_mfma_f32_32x32x16_f16(a, b, acc[nt], 0, 0, 0);
        }
    }

    // epilogue: tanh + dot(W2); reduce across the 32-lane column group
    float cb1[4], cw2[4];
    #pragma unroll
    for (int nt = 0; nt < 4; ++nt) {
        int col = nt * 32 + lrow;
        cb1[nt] = b1[col];
        cw2[nt] = W2[col];
    }
    const float bias2 = b2[0];

    #pragma unroll
    for (int r = 0; r < 16; ++r) {
        float s = 0.0f;
        #pragma unroll
        for (int nt = 0; nt < 4; ++nt)
            s += fast_tanh(acc[nt][r] + cb1[nt]) * cw2[nt];
        #pragma unroll
        for (int o = 1; o < 32; o <<= 1) s += __shfl_xor(s, o);  // halves reduce independently
        if (lrow == 0) {
            int rr = (r & 3) + 8 * (r >> 2) + 4 * lhalf;
            scores[m0 + rr] = s + bias2;
        }
    }
}

// ---------------------------------------------------------------------------
// K2: entmax-1.5 over S per batch row via bisection on tau.
// In-place scores -> weights; zero-inits ctx.
// ---------------------------------------------------------------------------
__global__ __launch_bounds__(256) void entmax_kernel(
    float* __restrict__ buf, float* __restrict__ ctx)
{
    __shared__ float sred[4];
    const int b = blockIdx.x, tid = threadIdx.x;
    float* p = buf + (size_t)b * SS;

    float z[16];
    #pragma unroll
    for (int j = 0; j < 16; ++j) z[j] = p[tid + j * 256] * 0.5f;

    float m = -1e30f;
    #pragma unroll
    for (int j = 0; j < 16; ++j) m = fmaxf(m, z[j]);
    #pragma unroll
    for (int o = 1; o < 64; o <<= 1) m = fmaxf(m, __shfl_xor(m, o));
    if ((tid & 63) == 0) sred[tid >> 6] = m;
    __syncthreads();
    m = fmaxf(fmaxf(sred[0], sred[1]), fmaxf(sred[2], sred[3]));
    __syncthreads();
    #pragma unroll
    for (int j = 0; j < 16; ++j) z[j] -= m;

    float lo = -1.0f, hi = 0.0f;
    for (int it = 0; it < 35; ++it) {
        float tau = 0.5f * (lo + hi);
        float s = 0.0f;
        #pragma unroll
        for (int j = 0; j < 16; ++j) {
            float d = fmaxf(z[j] - tau, 0.0f);
            s = fmaf(d, d, s);
        }
        #pragma unroll
        for (int o = 1; o < 64; o <<= 1) s += __shfl_xor(s, o);
        if ((tid & 63) == 0) sred[tid >> 6] = s;
        __syncthreads();
        s = sred[0] + sred[1] + sred[2] + sred[3];
        __syncthreads();
        if (s >= 1.0f) lo = tau; else hi = tau;
    }
    const float tau = 0.5f * (lo + hi);

    #pragma unroll
    for (int j = 0; j < 16; ++j) {
        float d = fmaxf(z[j] - tau, 0.0f);
        p[tid + j * 256] = d * d;
    }
    ctx[b * HH + tid] = 0.0f;
}

// ---------------------------------------------------------------------------
// K3: context[b,h] += sum_s X[b,s,h] * w[b,s]; entmax sparsity -> skip zeros
// (wave-uniform skip: only ~50 of 4096 rows per batch are nonzero)
// ---------------------------------------------------------------------------
__global__ __launch_bounds__(256) void context_kernel(
    const float* __restrict__ X, const float* __restrict__ w,
    float* __restrict__ ctx)
{
    const int b  = blockIdx.y;
    const int s0 = blockIdx.x * 128;
    const int h  = threadIdx.x;

    __shared__ float ws_[128];
    __shared__ int nzflag;
    if (h == 0) nzflag = 0;
    __syncthreads();
    if (h < 128) {
        float v = w[(size_t)b * SS + s0 + h];
        ws_[h] = v;
        if (v > 0.0f) nzflag = 1;
    }
    __syncthreads();
    if (!nzflag) return;

    float acc = 0.0f;
    const float* xp = X + ((size_t)b * SS + s0) * HH + h;
    #pragma unroll 4
    for (int i = 0; i < 128; ++i) {
        float wv = ws_[i];
        if (wv != 0.0f) acc = fmaf(xp[(size_t)i * HH], wv, acc);
    }
    atomicAdd(&ctx[b * HH + h], acc);
}

extern "C" void kernel_launch(void* const* d_in, const int* in_sizes, int n_in,
                              void* d_out, int out_size, void* d_ws, size_t ws_size,
                              hipStream_t stream) {
    const float* X  = (const float*)d_in[0];
    const float* W1 = (const float*)d_in[1];
    const float* b1 = (const float*)d_in[2];
    const float* W2 = (const float*)d_in[3];
    const float* b2 = (const float*)d_in[4];

    float* out = (float*)d_out;
    float* ctx = out;            // [64*256]
    float* wts = out + BB * HH;  // [64*4096] scores -> weights
    _Float16* Wt = (_Float16*)d_ws;  // [128][256] f16, 64 KB

    convert_w1<<<AA, HH, 0, stream>>>(W1, Wt);
    score_stream<<<(BB * SS) / 128, 256, 0, stream>>>(X, Wt, b1, W2, b2, wts);
    entmax_kernel<<<BB, 256, 0, stream>>>(wts, ctx);
    context_kernel<<<dim3(SS / 128, BB), 256, 0, stream>>>(X, wts, ctx);
}